// Round 1
// baseline (2441.185 us; speedup 1.0000x reference)
//
#include <hip/hip_runtime.h>
#include <cstdint>

#define B_ 2
#define S_ 8192
#define D_ 1024
#define H_ 16
#define HD_ 64
#define A_ 1024
#define SQ_ 7168

typedef unsigned short ushort_t;
typedef unsigned int uint_t;
typedef __bf16 bf16x8 __attribute__((ext_vector_type(8)));
typedef float floatx4 __attribute__((ext_vector_type(4)));
typedef ushort_t ushort8 __attribute__((ext_vector_type(8)));

__device__ __forceinline__ ushort_t f2bf(float f) {
  uint_t u = __builtin_bit_cast(uint_t, f);
  u += 0x7fffu + ((u >> 16) & 1u);   // RNE
  return (ushort_t)(u >> 16);
}
__device__ __forceinline__ float bf2f(ushort_t h) {
  uint_t u = ((uint_t)h) << 16;
  return __builtin_bit_cast(float, u);
}

// ---- fp32 -> bf16 convert (x), 8 elems/thread ----
__global__ __launch_bounds__(256) void cvt_x(const float* __restrict__ x,
                                             ushort_t* __restrict__ xb) {
  int i = (blockIdx.x * 256 + threadIdx.x) * 8;
  float4 a = *(const float4*)(x + i);
  float4 b = *(const float4*)(x + i + 4);
  ushort8 o;
  o[0] = f2bf(a.x); o[1] = f2bf(a.y); o[2] = f2bf(a.z); o[3] = f2bf(a.w);
  o[4] = f2bf(b.x); o[5] = f2bf(b.y); o[6] = f2bf(b.z); o[7] = f2bf(b.w);
  *(ushort8*)(xb + i) = o;
}

// ---- W (K=1024 x N) fp32 -> WT (N x 1024) bf16, LDS-tiled transpose ----
__global__ __launch_bounds__(256) void cvt_wT(const float* __restrict__ W,
                                              ushort_t* __restrict__ WT, int N) {
  __shared__ float t[32][33];
  int n0 = blockIdx.x * 32, k0 = blockIdx.y * 32;
  int tx = threadIdx.x, ty = threadIdx.y;
  #pragma unroll
  for (int i = ty; i < 32; i += 8) t[i][tx] = W[(uint64_t)(k0 + i) * N + n0 + tx];
  __syncthreads();
  #pragma unroll
  for (int i = ty; i < 32; i += 8)
    WT[(uint64_t)(n0 + i) * 1024 + k0 + tx] = f2bf(t[tx][i]);
}

// ---- bf16 MFMA GEMM, C = A(Mx1024) @ WT(Nx1024)^T, 128x128 tile ----
// MODE 0: A=xb anchor rows -> QKV epilogue (scatter to Qb/Kb/Vb, bf16)
// MODE 1: A=xb query rows  -> Q epilogue (Qb rows A_.., bf16)
// MODE 2: A=Ob             -> fp32 out + bias
template <int MODE>
__global__ __launch_bounds__(256) void gemm_bt(
    const ushort_t* __restrict__ Abase, const ushort_t* __restrict__ WT,
    const float* __restrict__ bias,
    ushort_t* __restrict__ Qb, ushort_t* __restrict__ Kb,
    ushort_t* __restrict__ Vb, float* __restrict__ outf) {
  __shared__ __align__(16) ushort_t At[128 * 32];
  __shared__ __align__(16) ushort_t Bt[128 * 32];
  const int t = threadIdx.x;
  const int lane = t & 63;
  const int quad = lane >> 4, ln = lane & 15;
  const int wave = t >> 6;
  const int wm = wave & 1, wn = wave >> 1;
  const int m0 = blockIdx.x * 128, n0 = blockIdx.y * 128;

  const int r0 = t >> 2, seg = t & 3;  // staging: 4 lanes per row, 16B each
  auto maprow = [&](int gm) -> int {
    if (MODE == 0) { int b = gm >> 10; int a = gm & 1023; return b * S_ + a; }
    if (MODE == 1) { int b = (gm >= SQ_) ? 1 : 0; int sq = gm - b * SQ_; return b * S_ + A_ + sq; }
    return gm;
  };
  const ushort_t* arow0 = Abase + (uint64_t)maprow(m0 + r0) * 1024;
  const ushort_t* arow1 = Abase + (uint64_t)maprow(m0 + 64 + r0) * 1024;
  const ushort_t* brow0 = WT + (uint64_t)(n0 + r0) * 1024;
  const ushort_t* brow1 = WT + (uint64_t)(n0 + 64 + r0) * 1024;

  floatx4 acc[4][4];
  #pragma unroll
  for (int i = 0; i < 4; ++i)
    #pragma unroll
    for (int j = 0; j < 4; ++j) acc[i][j] = (floatx4)0.0f;

  for (int k0 = 0; k0 < 1024; k0 += 32) {
    ushort8 la0 = *(const ushort8*)(arow0 + k0 + seg * 8);
    ushort8 la1 = *(const ushort8*)(arow1 + k0 + seg * 8);
    ushort8 lb0 = *(const ushort8*)(brow0 + k0 + seg * 8);
    ushort8 lb1 = *(const ushort8*)(brow1 + k0 + seg * 8);
    __syncthreads();  // previous iter's consumers done before overwrite
    *(ushort8*)&At[r0 * 32 + seg * 8] = la0;
    *(ushort8*)&At[(64 + r0) * 32 + seg * 8] = la1;
    *(ushort8*)&Bt[r0 * 32 + seg * 8] = lb0;
    *(ushort8*)&Bt[(64 + r0) * 32 + seg * 8] = lb1;
    __syncthreads();
    bf16x8 af[4], bfr[4];
    #pragma unroll
    for (int i = 0; i < 4; ++i)
      af[i] = *(const bf16x8*)&At[(wm * 64 + i * 16 + ln) * 32 + quad * 8];
    #pragma unroll
    for (int j = 0; j < 4; ++j)
      bfr[j] = *(const bf16x8*)&Bt[(wn * 64 + j * 16 + ln) * 32 + quad * 8];
    #pragma unroll
    for (int i = 0; i < 4; ++i)
      #pragma unroll
      for (int j = 0; j < 4; ++j)
        acc[i][j] = __builtin_amdgcn_mfma_f32_16x16x32_bf16(af[i], bfr[j], acc[i][j], 0, 0, 0);
  }

  // epilogue: C/D layout col=lane&15, row=quad*4+reg
  #pragma unroll
  for (int i = 0; i < 4; ++i) {
    #pragma unroll
    for (int j = 0; j < 4; ++j) {
      #pragma unroll
      for (int r = 0; r < 4; ++r) {
        int gm = m0 + wm * 64 + i * 16 + quad * 4 + r;
        int gn = n0 + wn * 64 + j * 16 + ln;
        float v = acc[i][j][r] + bias[gn];
        if (MODE == 2) {
          outf[(uint64_t)gm * 1024 + gn] = v;
        } else if (MODE == 0) {
          int b = gm >> 10, a = gm & 1023;
          int which = gn >> 10, h = (gn >> 6) & 15, d = gn & 63;
          ushort_t val = f2bf(v);
          if (which == 0)
            Qb[((uint64_t)(b * H_ + h) * S_ + a) * HD_ + d] = val;
          else if (which == 1)
            Kb[((uint64_t)(b * H_ + h) * A_ + a) * HD_ + d] = val;
          else
            Vb[((uint64_t)(b * H_ + h) * A_ + a) * HD_ + d] = val;
        } else {
          int b = (gm >= SQ_) ? 1 : 0; int sq = gm - b * SQ_;
          int h = gn >> 6, d = gn & 63;
          Qb[((uint64_t)(b * H_ + h) * S_ + (A_ + sq)) * HD_ + d] = f2bf(v);
        }
      }
    }
  }
}

// ---- attention: thread-per-query-row, fp32 softmax (no max needed: |s|<~8) ----
__global__ __launch_bounds__(256) void attn(const ushort_t* __restrict__ Qb,
                                            const ushort_t* __restrict__ Kb,
                                            const ushort_t* __restrict__ Vb,
                                            ushort_t* __restrict__ Ob) {
  __shared__ float Ksh[64 * 64];
  __shared__ float Vsh[64 * 64];
  const int t = threadIdx.x;
  const int bh = blockIdx.y;                // b*16+h
  const int qi = blockIdx.x * 256 + t;
  const int b = bh >> 4, h = bh & 15;

  float qreg[64];
  {
    const ushort_t* qp = Qb + ((uint64_t)bh * S_ + qi) * HD_;
    #pragma unroll
    for (int v = 0; v < 8; ++v) {
      ushort8 u = *(const ushort8*)(qp + v * 8);
      #pragma unroll
      for (int e = 0; e < 8; ++e) qreg[v * 8 + e] = bf2f(u[e]);
    }
  }
  float oacc[64];
  #pragma unroll
  for (int d = 0; d < 64; ++d) oacc[d] = 0.f;
  float lsum = 0.f;

  for (int kc = 0; kc < 16; ++kc) {
    const ushort_t* kp = Kb + ((uint64_t)bh * A_ + kc * 64) * HD_ + t * 16;
    const ushort_t* vp = Vb + ((uint64_t)bh * A_ + kc * 64) * HD_ + t * 16;
    ushort8 k0 = *(const ushort8*)(kp);
    ushort8 k1 = *(const ushort8*)(kp + 8);
    ushort8 v0 = *(const ushort8*)(vp);
    ushort8 v1 = *(const ushort8*)(vp + 8);
    __syncthreads();  // previous chunk consumed
    #pragma unroll
    for (int e = 0; e < 8; ++e) {
      Ksh[t * 16 + e] = bf2f(k0[e]);
      Ksh[t * 16 + 8 + e] = bf2f(k1[e]);
      Vsh[t * 16 + e] = bf2f(v0[e]);
      Vsh[t * 16 + 8 + e] = bf2f(v1[e]);
    }
    __syncthreads();
    #pragma unroll 1
    for (int j = 0; j < 64; ++j) {
      const float* krow = &Ksh[j * 64];
      float s0 = 0.f, s1 = 0.f, s2 = 0.f, s3 = 0.f;
      #pragma unroll
      for (int d = 0; d < 64; d += 4) {   // 4 independent FMA chains
        s0 += qreg[d + 0] * krow[d + 0];
        s1 += qreg[d + 1] * krow[d + 1];
        s2 += qreg[d + 2] * krow[d + 2];
        s3 += qreg[d + 3] * krow[d + 3];
      }
      float s = (s0 + s1) + (s2 + s3);
      float p = __expf(s * 0.125f);
      lsum += p;
      const float* vrow = &Vsh[j * 64];
      #pragma unroll
      for (int d = 0; d < 64; ++d) oacc[d] += p * vrow[d];
    }
  }
  float inv = 1.0f / lsum;
  ushort_t* op = Ob + ((uint64_t)(b * S_ + qi)) * D_ + h * HD_;
  #pragma unroll
  for (int v = 0; v < 8; ++v) {
    ushort8 o;
    #pragma unroll
    for (int e = 0; e < 8; ++e) o[e] = f2bf(oacc[v * 8 + e] * inv);
    *(ushort8*)(op + v * 8) = o;
  }
}

extern "C" void kernel_launch(void* const* d_in, const int* in_sizes, int n_in,
                              void* d_out, int out_size, void* d_ws, size_t ws_size,
                              hipStream_t stream) {
  (void)in_sizes; (void)n_in; (void)out_size; (void)ws_size;
  const float* x     = (const float*)d_in[0];
  const float* Wqkv  = (const float*)d_in[1];
  const float* bqkv  = (const float*)d_in[2];
  const float* Wq    = (const float*)d_in[3];
  const float* bq    = (const float*)d_in[4];
  const float* Wproj = (const float*)d_in[5];
  const float* bproj = (const float*)d_in[6];
  float* out = (float*)d_out;

  char* ws = (char*)d_ws;
  ushort_t* xb     = (ushort_t*)ws; ws += (size_t)B_ * S_ * D_ * 2;       // 32 MB
  ushort_t* wqkvT  = (ushort_t*)ws; ws += (size_t)3 * D_ * D_ * 2;        // 6 MB (3072x1024)
  ushort_t* wqT    = (ushort_t*)ws; ws += (size_t)D_ * D_ * 2;            // 2 MB
  ushort_t* wprojT = (ushort_t*)ws; ws += (size_t)D_ * D_ * 2;            // 2 MB
  ushort_t* Qb     = (ushort_t*)ws; ws += (size_t)B_ * H_ * S_ * HD_ * 2; // 32 MB (B,H,S,hd)
  ushort_t* Kb     = (ushort_t*)ws; ws += (size_t)B_ * H_ * A_ * HD_ * 2; // 4 MB
  ushort_t* Vb     = (ushort_t*)ws; ws += (size_t)B_ * H_ * A_ * HD_ * 2; // 4 MB
  ushort_t* Ob     = (ushort_t*)ws;                                       // 32 MB (B,S,D)

  cvt_x<<<dim3((B_ * S_ * D_) / (256 * 8)), dim3(256), 0, stream>>>(x, xb);
  cvt_wT<<<dim3(3072 / 32, 32), dim3(32, 8), 0, stream>>>(Wqkv, wqkvT, 3072);
  cvt_wT<<<dim3(1024 / 32, 32), dim3(32, 8), 0, stream>>>(Wq, wqT, 1024);
  cvt_wT<<<dim3(1024 / 32, 32), dim3(32, 8), 0, stream>>>(Wproj, wprojT, 1024);

  gemm_bt<0><<<dim3((B_ * A_) / 128, 3072 / 128), dim3(256), 0, stream>>>(
      xb, wqkvT, bqkv, Qb, Kb, Vb, nullptr);
  gemm_bt<1><<<dim3((B_ * SQ_) / 128, 1024 / 128), dim3(256), 0, stream>>>(
      xb, wqT, bq, Qb, nullptr, nullptr, nullptr);
  attn<<<dim3(S_ / 256, B_ * H_), dim3(256), 0, stream>>>(Qb, Kb, Vb, Ob);
  gemm_bt<2><<<dim3((B_ * S_) / 128, 1024 / 128), dim3(256), 0, stream>>>(
      Ob, wprojT, bproj, nullptr, nullptr, nullptr, out);
}

// Round 2
// 404.942 us; speedup vs baseline: 6.0285x; 6.0285x over previous
//
#include <hip/hip_runtime.h>
#include <cstdint>

#define B_ 2
#define S_ 8192
#define D_ 1024
#define H_ 16
#define HD_ 64
#define A_ 1024
#define SQ_ 7168

typedef unsigned short ushort_t;
typedef unsigned int uint_t;
typedef __bf16 bf16x8 __attribute__((ext_vector_type(8)));
typedef float floatx4 __attribute__((ext_vector_type(4)));
typedef ushort_t ushort8 __attribute__((ext_vector_type(8)));

__device__ __forceinline__ ushort_t f2bf(float f) {
  uint_t u = __builtin_bit_cast(uint_t, f);
  u += 0x7fffu + ((u >> 16) & 1u);   // RNE
  return (ushort_t)(u >> 16);
}
__device__ __forceinline__ float bf2f(ushort_t h) {
  uint_t u = ((uint_t)h) << 16;
  return __builtin_bit_cast(float, u);
}

// ---- fp32 -> bf16 convert (x), 8 elems/thread ----
__global__ __launch_bounds__(256) void cvt_x(const float* __restrict__ x,
                                             ushort_t* __restrict__ xb) {
  int i = (blockIdx.x * 256 + threadIdx.x) * 8;
  float4 a = *(const float4*)(x + i);
  float4 b = *(const float4*)(x + i + 4);
  ushort8 o;
  o[0] = f2bf(a.x); o[1] = f2bf(a.y); o[2] = f2bf(a.z); o[3] = f2bf(a.w);
  o[4] = f2bf(b.x); o[5] = f2bf(b.y); o[6] = f2bf(b.z); o[7] = f2bf(b.w);
  *(ushort8*)(xb + i) = o;
}

// ---- W (K=1024 x N) fp32 -> WT (N x 1024) bf16, LDS-tiled transpose ----
__global__ __launch_bounds__(256) void cvt_wT(const float* __restrict__ W,
                                              ushort_t* __restrict__ WT, int N) {
  __shared__ float t[32][33];
  int n0 = blockIdx.x * 32, k0 = blockIdx.y * 32;
  int tx = threadIdx.x, ty = threadIdx.y;
  #pragma unroll
  for (int i = ty; i < 32; i += 8) t[i][tx] = W[(uint64_t)(k0 + i) * N + n0 + tx];
  __syncthreads();
  #pragma unroll
  for (int i = ty; i < 32; i += 8)
    WT[(uint64_t)(n0 + i) * 1024 + k0 + tx] = f2bf(t[tx][i]);
}

// ---- bf16 MFMA GEMM, C = A(Mx1024) @ WT(Nx1024)^T, 128x128 tile ----
// MODE 0: A=xb anchor rows -> QKV epilogue (Q/K row-major, V TRANSPOSED (b,h,hd,A))
// MODE 1: A=xb query rows  -> Q epilogue (Qb rows A_.., bf16)
// MODE 2: A=Ob             -> fp32 out + bias
template <int MODE>
__global__ __launch_bounds__(256) void gemm_bt(
    const ushort_t* __restrict__ Abase, const ushort_t* __restrict__ WT,
    const float* __restrict__ bias,
    ushort_t* __restrict__ Qb, ushort_t* __restrict__ Kb,
    ushort_t* __restrict__ Vb, float* __restrict__ outf) {
  __shared__ __align__(16) ushort_t At[128 * 32];
  __shared__ __align__(16) ushort_t Bt[128 * 32];
  const int t = threadIdx.x;
  const int lane = t & 63;
  const int quad = lane >> 4, ln = lane & 15;
  const int wave = t >> 6;
  const int wm = wave & 1, wn = wave >> 1;
  const int m0 = blockIdx.x * 128, n0 = blockIdx.y * 128;

  const int r0 = t >> 2, seg = t & 3;  // staging: 4 lanes per row, 16B each
  auto maprow = [&](int gm) -> int {
    if (MODE == 0) { int b = gm >> 10; int a = gm & 1023; return b * S_ + a; }
    if (MODE == 1) { int b = (gm >= SQ_) ? 1 : 0; int sq = gm - b * SQ_; return b * S_ + A_ + sq; }
    return gm;
  };
  const ushort_t* arow0 = Abase + (uint64_t)maprow(m0 + r0) * 1024;
  const ushort_t* arow1 = Abase + (uint64_t)maprow(m0 + 64 + r0) * 1024;
  const ushort_t* brow0 = WT + (uint64_t)(n0 + r0) * 1024;
  const ushort_t* brow1 = WT + (uint64_t)(n0 + 64 + r0) * 1024;

  floatx4 acc[4][4];
  #pragma unroll
  for (int i = 0; i < 4; ++i)
    #pragma unroll
    for (int j = 0; j < 4; ++j) acc[i][j] = (floatx4)0.0f;

  for (int k0 = 0; k0 < 1024; k0 += 32) {
    ushort8 la0 = *(const ushort8*)(arow0 + k0 + seg * 8);
    ushort8 la1 = *(const ushort8*)(arow1 + k0 + seg * 8);
    ushort8 lb0 = *(const ushort8*)(brow0 + k0 + seg * 8);
    ushort8 lb1 = *(const ushort8*)(brow1 + k0 + seg * 8);
    __syncthreads();  // previous iter's consumers done before overwrite
    *(ushort8*)&At[r0 * 32 + seg * 8] = la0;
    *(ushort8*)&At[(64 + r0) * 32 + seg * 8] = la1;
    *(ushort8*)&Bt[r0 * 32 + seg * 8] = lb0;
    *(ushort8*)&Bt[(64 + r0) * 32 + seg * 8] = lb1;
    __syncthreads();
    bf16x8 af[4], bfr[4];
    #pragma unroll
    for (int i = 0; i < 4; ++i)
      af[i] = *(const bf16x8*)&At[(wm * 64 + i * 16 + ln) * 32 + quad * 8];
    #pragma unroll
    for (int j = 0; j < 4; ++j)
      bfr[j] = *(const bf16x8*)&Bt[(wn * 64 + j * 16 + ln) * 32 + quad * 8];
    #pragma unroll
    for (int i = 0; i < 4; ++i)
      #pragma unroll
      for (int j = 0; j < 4; ++j)
        acc[i][j] = __builtin_amdgcn_mfma_f32_16x16x32_bf16(af[i], bfr[j], acc[i][j], 0, 0, 0);
  }

  // epilogue: C/D layout col=lane&15, row=quad*4+reg
  #pragma unroll
  for (int i = 0; i < 4; ++i) {
    #pragma unroll
    for (int j = 0; j < 4; ++j) {
      #pragma unroll
      for (int r = 0; r < 4; ++r) {
        int gm = m0 + wm * 64 + i * 16 + quad * 4 + r;
        int gn = n0 + wn * 64 + j * 16 + ln;
        float v = acc[i][j][r] + bias[gn];
        if (MODE == 2) {
          outf[(uint64_t)gm * 1024 + gn] = v;
        } else if (MODE == 0) {
          int b = gm >> 10, a = gm & 1023;
          int which = gn >> 10, h = (gn >> 6) & 15, d = gn & 63;
          ushort_t val = f2bf(v);
          if (which == 0)
            Qb[((uint64_t)(b * H_ + h) * S_ + a) * HD_ + d] = val;
          else if (which == 1)
            Kb[((uint64_t)(b * H_ + h) * A_ + a) * HD_ + d] = val;
          else  // V stored transposed: (b,h,hd,A) for contiguous PV B-fragments
            Vb[((uint64_t)(b * H_ + h) * HD_ + d) * A_ + a] = val;
        } else {
          int b = (gm >= SQ_) ? 1 : 0; int sq = gm - b * SQ_;
          int h = gn >> 6, d = gn & 63;
          Qb[((uint64_t)(b * H_ + h) * S_ + (A_ + sq)) * HD_ + d] = f2bf(v);
        }
      }
    }
  }
}

// ---- MFMA flash attention: 128 Q-rows per block, 16 chunks of 64 keys ----
// No max-subtraction (scores bounded); softmax denom via ones-row in Vt (n-tile j=4).
__global__ __launch_bounds__(256) void attn_mfma(const ushort_t* __restrict__ Qb,
                                                 const ushort_t* __restrict__ Kb,
                                                 const ushort_t* __restrict__ Vb,
                                                 ushort_t* __restrict__ Ob) {
  __shared__ __align__(16) ushort_t Ks[64 * 72];   // keys x hd, pad 8
  __shared__ __align__(16) ushort_t Vt[80 * 72];   // hd(+ones row 64) x keys, pad 8
  __shared__ __align__(16) ushort_t Ps[128 * 72];  // qrows x keys, pad 8
  const int t = threadIdx.x;
  const int lane = t & 63;
  const int quad = lane >> 4, ln = lane & 15;
  const int wave = t >> 6;
  const int wm = wave & 1, wn = wave >> 1;  // S-stage: 2x2 over 128x64
  const int bh = blockIdx.y;
  const int b = bh >> 4, h = bh & 15;
  const int m0 = blockIdx.x * 128;

  // Q fragments in registers: rows m0+wm*64+i*16+ln, cols ks*32+quad*8
  bf16x8 qf[4][2];
  {
    const ushort_t* qbase = Qb + ((uint64_t)bh * S_ + m0 + wm * 64 + ln) * HD_ + quad * 8;
    #pragma unroll
    for (int i = 0; i < 4; ++i)
      #pragma unroll
      for (int ks = 0; ks < 2; ++ks)
        qf[i][ks] = *(const bf16x8*)(qbase + (uint64_t)(i * 16) * HD_ + ks * 32);
  }
  // ones row (row 64 of Vt) -> PV n-tile j=4 col 64 accumulates the row sum
  if (t < 64) Vt[64 * 72 + t] = 0x3F80;  // bf16 1.0

  floatx4 oacc[2][5];
  #pragma unroll
  for (int i = 0; i < 2; ++i)
    #pragma unroll
    for (int j = 0; j < 5; ++j) oacc[i][j] = (floatx4)0.0f;

  const ushort_t* kcbase = Kb + (uint64_t)bh * A_ * HD_;
  const ushort_t* vcbase = Vb + (uint64_t)bh * HD_ * A_;
  const int srow = t >> 2, sseg = t & 3;  // staging: 4 threads/row, 16 elems each

  for (int kc = 0; kc < 16; ++kc) {
    const ushort_t* kg = kcbase + (uint64_t)(kc * 64 + srow) * 64 + sseg * 16;
    const ushort_t* vg = vcbase + (uint64_t)srow * A_ + kc * 64 + sseg * 16;
    ushort8 k0 = *(const ushort8*)kg;
    ushort8 k1 = *(const ushort8*)(kg + 8);
    ushort8 v0 = *(const ushort8*)vg;
    ushort8 v1 = *(const ushort8*)(vg + 8);
    __syncthreads();  // prev chunk's PV reads of Ks/Vt/Ps done
    *(ushort8*)&Ks[srow * 72 + sseg * 16] = k0;
    *(ushort8*)&Ks[srow * 72 + sseg * 16 + 8] = k1;
    *(ushort8*)&Vt[srow * 72 + sseg * 16] = v0;
    *(ushort8*)&Vt[srow * 72 + sseg * 16 + 8] = v1;
    __syncthreads();

    // S = Q @ K^T : wave computes 64(m) x 32(n)
    floatx4 sacc[4][2];
    #pragma unroll
    for (int i = 0; i < 4; ++i)
      #pragma unroll
      for (int j = 0; j < 2; ++j) sacc[i][j] = (floatx4)0.0f;
    #pragma unroll
    for (int ks = 0; ks < 2; ++ks) {
      bf16x8 bfr[2];
      #pragma unroll
      for (int j = 0; j < 2; ++j)
        bfr[j] = *(const bf16x8*)&Ks[(wn * 32 + j * 16 + ln) * 72 + ks * 32 + quad * 8];
      #pragma unroll
      for (int i = 0; i < 4; ++i)
        #pragma unroll
        for (int j = 0; j < 2; ++j)
          sacc[i][j] = __builtin_amdgcn_mfma_f32_16x16x32_bf16(qf[i][ks], bfr[j], sacc[i][j], 0, 0, 0);
    }
    // P = exp(S/8), bf16 -> LDS row-major (C-layout -> A-layout round trip)
    #pragma unroll
    for (int i = 0; i < 4; ++i)
      #pragma unroll
      for (int j = 0; j < 2; ++j)
        #pragma unroll
        for (int r = 0; r < 4; ++r) {
          float p = __expf(sacc[i][j][r] * 0.125f);
          Ps[(wm * 64 + i * 16 + quad * 4 + r) * 72 + wn * 32 + j * 16 + ln] = f2bf(p);
        }
    __syncthreads();

    // O += P @ V : wave owns 32 rows (wave*32), n-tiles j=0..4 (j=4 = row sum)
    #pragma unroll
    for (int ks = 0; ks < 2; ++ks) {
      bf16x8 af[2];
      #pragma unroll
      for (int i2 = 0; i2 < 2; ++i2)
        af[i2] = *(const bf16x8*)&Ps[(wave * 32 + i2 * 16 + ln) * 72 + ks * 32 + quad * 8];
      bf16x8 bv[5];
      #pragma unroll
      for (int j = 0; j < 5; ++j)
        bv[j] = *(const bf16x8*)&Vt[(j * 16 + ln) * 72 + ks * 32 + quad * 8];
      #pragma unroll
      for (int i2 = 0; i2 < 2; ++i2)
        #pragma unroll
        for (int j = 0; j < 5; ++j)
          oacc[i2][j] = __builtin_amdgcn_mfma_f32_16x16x32_bf16(af[i2], bv[j], oacc[i2][j], 0, 0, 0);
    }
  }

  // normalize + store: row sum lives in oacc[i2][4][r] on ln==0 lanes
  #pragma unroll
  for (int i2 = 0; i2 < 2; ++i2) {
    #pragma unroll
    for (int r = 0; r < 4; ++r) {
      float lsum = __shfl(oacc[i2][4][r], lane & 48);  // bcast from ln==0 of this quad
      float inv = 1.0f / lsum;
      int qrow = m0 + wave * 32 + i2 * 16 + quad * 4 + r;
      ushort_t* op = Ob + ((uint64_t)b * S_ + qrow) * D_ + h * HD_;
      #pragma unroll
      for (int j = 0; j < 4; ++j)
        op[j * 16 + ln] = f2bf(oacc[i2][j][r] * inv);
    }
  }
}

extern "C" void kernel_launch(void* const* d_in, const int* in_sizes, int n_in,
                              void* d_out, int out_size, void* d_ws, size_t ws_size,
                              hipStream_t stream) {
  (void)in_sizes; (void)n_in; (void)out_size; (void)ws_size;
  const float* x     = (const float*)d_in[0];
  const float* Wqkv  = (const float*)d_in[1];
  const float* bqkv  = (const float*)d_in[2];
  const float* Wq    = (const float*)d_in[3];
  const float* bq    = (const float*)d_in[4];
  const float* Wproj = (const float*)d_in[5];
  const float* bproj = (const float*)d_in[6];
  float* out = (float*)d_out;

  char* ws = (char*)d_ws;
  ushort_t* xb     = (ushort_t*)ws; ws += (size_t)B_ * S_ * D_ * 2;       // 32 MB
  ushort_t* wqkvT  = (ushort_t*)ws; ws += (size_t)3 * D_ * D_ * 2;        // 6 MB (3072x1024)
  ushort_t* wqT    = (ushort_t*)ws; ws += (size_t)D_ * D_ * 2;            // 2 MB
  ushort_t* wprojT = (ushort_t*)ws; ws += (size_t)D_ * D_ * 2;            // 2 MB
  ushort_t* Qb     = (ushort_t*)ws; ws += (size_t)B_ * H_ * S_ * HD_ * 2; // 32 MB (B,H,S,hd)
  ushort_t* Kb     = (ushort_t*)ws; ws += (size_t)B_ * H_ * A_ * HD_ * 2; // 4 MB (B,H,A,hd)
  ushort_t* Vb     = (ushort_t*)ws; ws += (size_t)B_ * H_ * A_ * HD_ * 2; // 4 MB (B,H,hd,A)
  ushort_t* Ob     = (ushort_t*)ws;                                       // 32 MB (B,S,D)

  cvt_x<<<dim3((B_ * S_ * D_) / (256 * 8)), dim3(256), 0, stream>>>(x, xb);
  cvt_wT<<<dim3(3072 / 32, 32), dim3(32, 8), 0, stream>>>(Wqkv, wqkvT, 3072);
  cvt_wT<<<dim3(1024 / 32, 32), dim3(32, 8), 0, stream>>>(Wq, wqT, 1024);
  cvt_wT<<<dim3(1024 / 32, 32), dim3(32, 8), 0, stream>>>(Wproj, wprojT, 1024);

  gemm_bt<0><<<dim3((B_ * A_) / 128, 3072 / 128), dim3(256), 0, stream>>>(
      xb, wqkvT, bqkv, Qb, Kb, Vb, nullptr);
  gemm_bt<1><<<dim3((B_ * SQ_) / 128, 1024 / 128), dim3(256), 0, stream>>>(
      xb, wqT, bq, Qb, nullptr, nullptr, nullptr);
  attn_mfma<<<dim3(S_ / 128, B_ * H_), dim3(256), 0, stream>>>(Qb, Kb, Vb, Ob);
  gemm_bt<2><<<dim3((B_ * S_) / 128, 1024 / 128), dim3(256), 0, stream>>>(
      Ob, wprojT, bproj, nullptr, nullptr, nullptr, out);
}

// Round 3
// 393.675 us; speedup vs baseline: 6.2010x; 1.0286x over previous
//
#include <hip/hip_runtime.h>
#include <cstdint>

#define B_ 2
#define S_ 8192
#define D_ 1024
#define H_ 16
#define HD_ 64
#define A_ 1024
#define SQ_ 7168

typedef unsigned short ushort_t;
typedef unsigned int uint_t;
typedef __bf16 bf16x8 __attribute__((ext_vector_type(8)));
typedef float floatx4 __attribute__((ext_vector_type(4)));
typedef ushort_t ushort8 __attribute__((ext_vector_type(8)));

__device__ __forceinline__ ushort_t f2bf(float f) {
  uint_t u = __builtin_bit_cast(uint_t, f);
  u += 0x7fffu + ((u >> 16) & 1u);   // RNE
  return (ushort_t)(u >> 16);
}
__device__ __forceinline__ float bf2f(ushort_t h) {
  uint_t u = ((uint_t)h) << 16;
  return __builtin_bit_cast(float, u);
}

// async global->LDS, 16B per lane; LDS dest = wave-uniform base + lane*16
__device__ __forceinline__ void glds16(const ushort_t* g, ushort_t* l) {
  __builtin_amdgcn_global_load_lds(
      (const __attribute__((address_space(1))) void*)g,
      (__attribute__((address_space(3))) void*)l, 16, 0, 0);
}

// ---- fp32 -> bf16 convert (x), 8 elems/thread ----
__global__ __launch_bounds__(256) void cvt_x(const float* __restrict__ x,
                                             ushort_t* __restrict__ xb) {
  int i = (blockIdx.x * 256 + threadIdx.x) * 8;
  float4 a = *(const float4*)(x + i);
  float4 b = *(const float4*)(x + i + 4);
  ushort8 o;
  o[0] = f2bf(a.x); o[1] = f2bf(a.y); o[2] = f2bf(a.z); o[3] = f2bf(a.w);
  o[4] = f2bf(b.x); o[5] = f2bf(b.y); o[6] = f2bf(b.z); o[7] = f2bf(b.w);
  *(ushort8*)(xb + i) = o;
}

// ---- W (K=1024 x N) fp32 -> WT (N x 1024) bf16, LDS-tiled transpose ----
__global__ __launch_bounds__(256) void cvt_wT(const float* __restrict__ W,
                                              ushort_t* __restrict__ WT, int N) {
  __shared__ float t[32][33];
  int n0 = blockIdx.x * 32, k0 = blockIdx.y * 32;
  int tx = threadIdx.x, ty = threadIdx.y;
  #pragma unroll
  for (int i = ty; i < 32; i += 8) t[i][tx] = W[(uint64_t)(k0 + i) * N + n0 + tx];
  __syncthreads();
  #pragma unroll
  for (int i = ty; i < 32; i += 8)
    WT[(uint64_t)(n0 + i) * 1024 + k0 + tx] = f2bf(t[tx][i]);
}

// ---- bf16 MFMA GEMM, C = A(Mx1024) @ WT(Nx1024)^T, 128x128 tile ----
// m97 structure: global_load_lds width-16 staging between two barriers.
// MODE 0: A=xb anchor rows -> QKV epilogue (Q/K row-major, V TRANSPOSED (b,h,hd,A))
// MODE 1: A=xb query rows  -> Q epilogue (Qb rows A_.., bf16)
// MODE 2: A=Ob             -> fp32 out + bias
template <int MODE>
__global__ __launch_bounds__(256) void gemm_bt(
    const ushort_t* __restrict__ Abase, const ushort_t* __restrict__ WT,
    const float* __restrict__ bias,
    ushort_t* __restrict__ Qb, ushort_t* __restrict__ Kb,
    ushort_t* __restrict__ Vb, float* __restrict__ outf) {
  __shared__ __align__(16) ushort_t At[128 * 32];
  __shared__ __align__(16) ushort_t Bt[128 * 32];
  const int t = threadIdx.x;
  const int lane = t & 63;
  const int quad = lane >> 4, ln = lane & 15;
  const int wave = t >> 6;
  const int wm = wave & 1, wn = wave >> 1;
  const int m0 = blockIdx.x * 128, n0 = blockIdx.y * 128;

  const int r0 = t >> 2, seg = t & 3;  // staging: 4 lanes per row, 16B each
  auto maprow = [&](int gm) -> int {
    if (MODE == 0) { int b = gm >> 10; int a = gm & 1023; return b * S_ + a; }
    if (MODE == 1) { int b = (gm >= SQ_) ? 1 : 0; int sq = gm - b * SQ_; return b * S_ + A_ + sq; }
    return gm;
  };
  const ushort_t* arow0 = Abase + (uint64_t)maprow(m0 + r0) * 1024;
  const ushort_t* arow1 = Abase + (uint64_t)maprow(m0 + 64 + r0) * 1024;
  const ushort_t* brow0 = WT + (uint64_t)(n0 + r0) * 1024;
  const ushort_t* brow1 = WT + (uint64_t)(n0 + 64 + r0) * 1024;
  // LDS bases: thread t's 16B lands at byte t*16 relative to the issue base
  ushort_t* At_lo = (ushort_t*)((char*)At + wave * 1024);
  ushort_t* At_hi = (ushort_t*)((char*)At + 4096 + wave * 1024);
  ushort_t* Bt_lo = (ushort_t*)((char*)Bt + wave * 1024);
  ushort_t* Bt_hi = (ushort_t*)((char*)Bt + 4096 + wave * 1024);

  floatx4 acc[4][4];
  #pragma unroll
  for (int i = 0; i < 4; ++i)
    #pragma unroll
    for (int j = 0; j < 4; ++j) acc[i][j] = (floatx4)0.0f;

  for (int k0 = 0; k0 < 1024; k0 += 32) {
    __syncthreads();  // previous iter's consumers done before overwrite
    glds16(arow0 + k0 + seg * 8, At_lo);
    glds16(arow1 + k0 + seg * 8, At_hi);
    glds16(brow0 + k0 + seg * 8, Bt_lo);
    glds16(brow1 + k0 + seg * 8, Bt_hi);
    __syncthreads();  // vmcnt drained by compiler before barrier
    bf16x8 af[4], bfr[4];
    #pragma unroll
    for (int i = 0; i < 4; ++i)
      af[i] = *(const bf16x8*)&At[(wm * 64 + i * 16 + ln) * 32 + quad * 8];
    #pragma unroll
    for (int j = 0; j < 4; ++j)
      bfr[j] = *(const bf16x8*)&Bt[(wn * 64 + j * 16 + ln) * 32 + quad * 8];
    #pragma unroll
    for (int i = 0; i < 4; ++i)
      #pragma unroll
      for (int j = 0; j < 4; ++j)
        acc[i][j] = __builtin_amdgcn_mfma_f32_16x16x32_bf16(af[i], bfr[j], acc[i][j], 0, 0, 0);
  }

  // epilogue: C/D layout col=lane&15, row=quad*4+reg
  #pragma unroll
  for (int i = 0; i < 4; ++i) {
    #pragma unroll
    for (int j = 0; j < 4; ++j) {
      #pragma unroll
      for (int r = 0; r < 4; ++r) {
        int gm = m0 + wm * 64 + i * 16 + quad * 4 + r;
        int gn = n0 + wn * 64 + j * 16 + ln;
        float v = acc[i][j][r] + bias[gn];
        if (MODE == 2) {
          outf[(uint64_t)gm * 1024 + gn] = v;
        } else if (MODE == 0) {
          int b = gm >> 10, a = gm & 1023;
          int which = gn >> 10, h = (gn >> 6) & 15, d = gn & 63;
          ushort_t val = f2bf(v);
          if (which == 0)
            Qb[((uint64_t)(b * H_ + h) * S_ + a) * HD_ + d] = val;
          else if (which == 1)
            Kb[((uint64_t)(b * H_ + h) * A_ + a) * HD_ + d] = val;
          else  // V stored transposed: (b,h,hd,A) for contiguous PV B-fragments
            Vb[((uint64_t)(b * H_ + h) * HD_ + d) * A_ + a] = val;
        } else {
          int b = (gm >= SQ_) ? 1 : 0; int sq = gm - b * SQ_;
          int h = gn >> 6, d = gn & 63;
          Qb[((uint64_t)(b * H_ + h) * S_ + (A_ + sq)) * HD_ + d] = f2bf(v);
        }
      }
    }
  }
}

// ---- MFMA flash attention: 128 Q-rows per block, 16 chunks of 64 keys ----
// No max-subtraction (scores bounded); softmax denom via ones-row in Vt (n-tile j=4).
__global__ __launch_bounds__(256) void attn_mfma(const ushort_t* __restrict__ Qb,
                                                 const ushort_t* __restrict__ Kb,
                                                 const ushort_t* __restrict__ Vb,
                                                 ushort_t* __restrict__ Ob) {
  __shared__ __align__(16) ushort_t Ks[64 * 72];   // keys x hd, pad 8
  __shared__ __align__(16) ushort_t Vt[80 * 72];   // hd(+ones row 64) x keys, pad 8
  __shared__ __align__(16) ushort_t Ps[128 * 72];  // qrows x keys, pad 8
  const int t = threadIdx.x;
  const int lane = t & 63;
  const int quad = lane >> 4, ln = lane & 15;
  const int wave = t >> 6;
  const int wm = wave & 1, wn = wave >> 1;  // S-stage: 2x2 over 128x64
  const int bh = blockIdx.y;
  const int b = bh >> 4, h = bh & 15;
  const int m0 = blockIdx.x * 128;

  // Q fragments in registers: rows m0+wm*64+i*16+ln, cols ks*32+quad*8
  bf16x8 qf[4][2];
  {
    const ushort_t* qbase = Qb + ((uint64_t)bh * S_ + m0 + wm * 64 + ln) * HD_ + quad * 8;
    #pragma unroll
    for (int i = 0; i < 4; ++i)
      #pragma unroll
      for (int ks = 0; ks < 2; ++ks)
        qf[i][ks] = *(const bf16x8*)(qbase + (uint64_t)(i * 16) * HD_ + ks * 32);
  }
  // ones row (row 64 of Vt) -> PV n-tile j=4 col 64 accumulates the row sum
  if (t < 64) Vt[64 * 72 + t] = 0x3F80;  // bf16 1.0

  floatx4 oacc[2][5];
  #pragma unroll
  for (int i = 0; i < 2; ++i)
    #pragma unroll
    for (int j = 0; j < 5; ++j) oacc[i][j] = (floatx4)0.0f;

  const ushort_t* kcbase = Kb + (uint64_t)bh * A_ * HD_;
  const ushort_t* vcbase = Vb + (uint64_t)bh * HD_ * A_;
  const int srow = t >> 2, sseg = t & 3;  // staging: 4 threads/row, 16 elems each

  for (int kc = 0; kc < 16; ++kc) {
    const ushort_t* kg = kcbase + (uint64_t)(kc * 64 + srow) * 64 + sseg * 16;
    const ushort_t* vg = vcbase + (uint64_t)srow * A_ + kc * 64 + sseg * 16;
    ushort8 k0 = *(const ushort8*)kg;
    ushort8 k1 = *(const ushort8*)(kg + 8);
    ushort8 v0 = *(const ushort8*)vg;
    ushort8 v1 = *(const ushort8*)(vg + 8);
    __syncthreads();  // prev chunk's PV reads of Ks/Vt/Ps done
    *(ushort8*)&Ks[srow * 72 + sseg * 16] = k0;
    *(ushort8*)&Ks[srow * 72 + sseg * 16 + 8] = k1;
    *(ushort8*)&Vt[srow * 72 + sseg * 16] = v0;
    *(ushort8*)&Vt[srow * 72 + sseg * 16 + 8] = v1;
    __syncthreads();

    // S = Q @ K^T : wave computes 64(m) x 32(n)
    floatx4 sacc[4][2];
    #pragma unroll
    for (int i = 0; i < 4; ++i)
      #pragma unroll
      for (int j = 0; j < 2; ++j) sacc[i][j] = (floatx4)0.0f;
    #pragma unroll
    for (int ks = 0; ks < 2; ++ks) {
      bf16x8 bfr[2];
      #pragma unroll
      for (int j = 0; j < 2; ++j)
        bfr[j] = *(const bf16x8*)&Ks[(wn * 32 + j * 16 + ln) * 72 + ks * 32 + quad * 8];
      #pragma unroll
      for (int i = 0; i < 4; ++i)
        #pragma unroll
        for (int j = 0; j < 2; ++j)
          sacc[i][j] = __builtin_amdgcn_mfma_f32_16x16x32_bf16(qf[i][ks], bfr[j], sacc[i][j], 0, 0, 0);
    }
    // P = exp(S/8), bf16 -> LDS row-major (C-layout -> A-layout round trip)
    #pragma unroll
    for (int i = 0; i < 4; ++i)
      #pragma unroll
      for (int j = 0; j < 2; ++j)
        #pragma unroll
        for (int r = 0; r < 4; ++r) {
          float p = __expf(sacc[i][j][r] * 0.125f);
          Ps[(wm * 64 + i * 16 + quad * 4 + r) * 72 + wn * 32 + j * 16 + ln] = f2bf(p);
        }
    __syncthreads();

    // O += P @ V : wave owns 32 rows (wave*32), n-tiles j=0..4 (j=4 = row sum)
    #pragma unroll
    for (int ks = 0; ks < 2; ++ks) {
      bf16x8 af[2];
      #pragma unroll
      for (int i2 = 0; i2 < 2; ++i2)
        af[i2] = *(const bf16x8*)&Ps[(wave * 32 + i2 * 16 + ln) * 72 + ks * 32 + quad * 8];
      bf16x8 bv[5];
      #pragma unroll
      for (int j = 0; j < 5; ++j)
        bv[j] = *(const bf16x8*)&Vt[(j * 16 + ln) * 72 + ks * 32 + quad * 8];
      #pragma unroll
      for (int i2 = 0; i2 < 2; ++i2)
        #pragma unroll
        for (int j = 0; j < 5; ++j)
          oacc[i2][j] = __builtin_amdgcn_mfma_f32_16x16x32_bf16(af[i2], bv[j], oacc[i2][j], 0, 0, 0);
    }
  }

  // normalize + store: row sum lives in oacc[i2][4][r] on ln==0 lanes
  #pragma unroll
  for (int i2 = 0; i2 < 2; ++i2) {
    #pragma unroll
    for (int r = 0; r < 4; ++r) {
      float lsum = __shfl(oacc[i2][4][r], lane & 48);  // bcast from ln==0 of this quad
      float inv = 1.0f / lsum;
      int qrow = m0 + wave * 32 + i2 * 16 + quad * 4 + r;
      ushort_t* op = Ob + ((uint64_t)b * S_ + qrow) * D_ + h * HD_;
      #pragma unroll
      for (int j = 0; j < 4; ++j)
        op[j * 16 + ln] = f2bf(oacc[i2][j][r] * inv);
    }
  }
}

extern "C" void kernel_launch(void* const* d_in, const int* in_sizes, int n_in,
                              void* d_out, int out_size, void* d_ws, size_t ws_size,
                              hipStream_t stream) {
  (void)in_sizes; (void)n_in; (void)out_size; (void)ws_size;
  const float* x     = (const float*)d_in[0];
  const float* Wqkv  = (const float*)d_in[1];
  const float* bqkv  = (const float*)d_in[2];
  const float* Wq    = (const float*)d_in[3];
  const float* bq    = (const float*)d_in[4];
  const float* Wproj = (const float*)d_in[5];
  const float* bproj = (const float*)d_in[6];
  float* out = (float*)d_out;

  char* ws = (char*)d_ws;
  ushort_t* xb     = (ushort_t*)ws; ws += (size_t)B_ * S_ * D_ * 2;       // 32 MB
  ushort_t* wqkvT  = (ushort_t*)ws; ws += (size_t)3 * D_ * D_ * 2;        // 6 MB (3072x1024)
  ushort_t* wqT    = (ushort_t*)ws; ws += (size_t)D_ * D_ * 2;            // 2 MB
  ushort_t* wprojT = (ushort_t*)ws; ws += (size_t)D_ * D_ * 2;            // 2 MB
  ushort_t* Qb     = (ushort_t*)ws; ws += (size_t)B_ * H_ * S_ * HD_ * 2; // 32 MB (B,H,S,hd)
  ushort_t* Kb     = (ushort_t*)ws; ws += (size_t)B_ * H_ * A_ * HD_ * 2; // 4 MB (B,H,A,hd)
  ushort_t* Vb     = (ushort_t*)ws; ws += (size_t)B_ * H_ * A_ * HD_ * 2; // 4 MB (B,H,hd,A)
  ushort_t* Ob     = (ushort_t*)ws;                                       // 32 MB (B,S,D)

  cvt_x<<<dim3((B_ * S_ * D_) / (256 * 8)), dim3(256), 0, stream>>>(x, xb);
  cvt_wT<<<dim3(3072 / 32, 32), dim3(32, 8), 0, stream>>>(Wqkv, wqkvT, 3072);
  cvt_wT<<<dim3(1024 / 32, 32), dim3(32, 8), 0, stream>>>(Wq, wqT, 1024);
  cvt_wT<<<dim3(1024 / 32, 32), dim3(32, 8), 0, stream>>>(Wproj, wprojT, 1024);

  gemm_bt<0><<<dim3((B_ * A_) / 128, 3072 / 128), dim3(256), 0, stream>>>(
      xb, wqkvT, bqkv, Qb, Kb, Vb, nullptr);
  gemm_bt<1><<<dim3((B_ * SQ_) / 128, 1024 / 128), dim3(256), 0, stream>>>(
      xb, wqT, bq, Qb, nullptr, nullptr, nullptr);
  attn_mfma<<<dim3(S_ / 128, B_ * H_), dim3(256), 0, stream>>>(Qb, Kb, Vb, Ob);
  gemm_bt<2><<<dim3((B_ * S_) / 128, 1024 / 128), dim3(256), 0, stream>>>(
      Ob, wprojT, bproj, nullptr, nullptr, nullptr, out);
}

// Round 4
// 391.611 us; speedup vs baseline: 6.2337x; 1.0053x over previous
//
#include <hip/hip_runtime.h>
#include <cstdint>

#define B_ 2
#define S_ 8192
#define D_ 1024
#define H_ 16
#define HD_ 64
#define A_ 1024
#define SQ_ 7168

typedef unsigned short ushort_t;
typedef unsigned int uint_t;
typedef __bf16 bf16x8 __attribute__((ext_vector_type(8)));
typedef float floatx4 __attribute__((ext_vector_type(4)));
typedef ushort_t ushort8 __attribute__((ext_vector_type(8)));
typedef uint_t uint2v __attribute__((ext_vector_type(2)));

__device__ __forceinline__ ushort_t f2bf(float f) {
  uint_t u = __builtin_bit_cast(uint_t, f);
  u += 0x7fffu + ((u >> 16) & 1u);   // RNE
  return (ushort_t)(u >> 16);
}
__device__ __forceinline__ float bf2f(ushort_t h) {
  uint_t u = ((uint_t)h) << 16;
  return __builtin_bit_cast(float, u);
}

// async global->LDS, 16B per lane; LDS dest = wave-uniform base + lane*16
__device__ __forceinline__ void glds16(const ushort_t* g, ushort_t* l) {
  __builtin_amdgcn_global_load_lds(
      (const __attribute__((address_space(1))) void*)g,
      (__attribute__((address_space(3))) void*)l, 16, 0, 0);
}

// ---- fp32 -> bf16 convert (x), 8 elems/thread ----
__global__ __launch_bounds__(256) void cvt_x(const float* __restrict__ x,
                                             ushort_t* __restrict__ xb) {
  int i = (blockIdx.x * 256 + threadIdx.x) * 8;
  float4 a = *(const float4*)(x + i);
  float4 b = *(const float4*)(x + i + 4);
  ushort8 o;
  o[0] = f2bf(a.x); o[1] = f2bf(a.y); o[2] = f2bf(a.z); o[3] = f2bf(a.w);
  o[4] = f2bf(b.x); o[5] = f2bf(b.y); o[6] = f2bf(b.z); o[7] = f2bf(b.w);
  *(ushort8*)(xb + i) = o;
}

// ---- W (K=1024 x N) fp32 -> WT (N x 1024) bf16, LDS-tiled transpose ----
__global__ __launch_bounds__(256) void cvt_wT(const float* __restrict__ W,
                                              ushort_t* __restrict__ WT, int N) {
  __shared__ float t[32][33];
  int n0 = blockIdx.x * 32, k0 = blockIdx.y * 32;
  int tx = threadIdx.x, ty = threadIdx.y;
  #pragma unroll
  for (int i = ty; i < 32; i += 8) t[i][tx] = W[(uint64_t)(k0 + i) * N + n0 + tx];
  __syncthreads();
  #pragma unroll
  for (int i = ty; i < 32; i += 8)
    WT[(uint64_t)(n0 + i) * 1024 + k0 + tx] = f2bf(t[tx][i]);
}

// ---- bf16 MFMA GEMM, C = A(Mx1024) @ WT(Nx1024)^T, 128x128 tile ----
// m97 structure: global_load_lds width-16 staging between two barriers.
// MODE 0: A=xb anchor rows -> QKV epilogue (Q/K row-major, V TRANSPOSED (b,h,hd,A))
// MODE 1: A=xb query rows  -> Q epilogue (Qb rows A_.., bf16)
// MODE 2: A=Ob             -> fp32 out + bias
template <int MODE>
__global__ __launch_bounds__(256) void gemm_bt(
    const ushort_t* __restrict__ Abase, const ushort_t* __restrict__ WT,
    const float* __restrict__ bias,
    ushort_t* __restrict__ Qb, ushort_t* __restrict__ Kb,
    ushort_t* __restrict__ Vb, float* __restrict__ outf) {
  __shared__ __align__(16) ushort_t At[128 * 32];
  __shared__ __align__(16) ushort_t Bt[128 * 32];
  const int t = threadIdx.x;
  const int lane = t & 63;
  const int quad = lane >> 4, ln = lane & 15;
  const int wave = t >> 6;
  const int wm = wave & 1, wn = wave >> 1;
  const int m0 = blockIdx.x * 128, n0 = blockIdx.y * 128;

  const int r0 = t >> 2, seg = t & 3;  // staging: 4 lanes per row, 16B each
  auto maprow = [&](int gm) -> int {
    if (MODE == 0) { int b = gm >> 10; int a = gm & 1023; return b * S_ + a; }
    if (MODE == 1) { int b = (gm >= SQ_) ? 1 : 0; int sq = gm - b * SQ_; return b * S_ + A_ + sq; }
    return gm;
  };
  const ushort_t* arow0 = Abase + (uint64_t)maprow(m0 + r0) * 1024;
  const ushort_t* arow1 = Abase + (uint64_t)maprow(m0 + 64 + r0) * 1024;
  const ushort_t* brow0 = WT + (uint64_t)(n0 + r0) * 1024;
  const ushort_t* brow1 = WT + (uint64_t)(n0 + 64 + r0) * 1024;
  // LDS bases: thread t's 16B lands at byte t*16 relative to the issue base
  ushort_t* At_lo = (ushort_t*)((char*)At + wave * 1024);
  ushort_t* At_hi = (ushort_t*)((char*)At + 4096 + wave * 1024);
  ushort_t* Bt_lo = (ushort_t*)((char*)Bt + wave * 1024);
  ushort_t* Bt_hi = (ushort_t*)((char*)Bt + 4096 + wave * 1024);

  floatx4 acc[4][4];
  #pragma unroll
  for (int i = 0; i < 4; ++i)
    #pragma unroll
    for (int j = 0; j < 4; ++j) acc[i][j] = (floatx4)0.0f;

  for (int k0 = 0; k0 < 1024; k0 += 32) {
    __syncthreads();  // previous iter's consumers done before overwrite
    glds16(arow0 + k0 + seg * 8, At_lo);
    glds16(arow1 + k0 + seg * 8, At_hi);
    glds16(brow0 + k0 + seg * 8, Bt_lo);
    glds16(brow1 + k0 + seg * 8, Bt_hi);
    __syncthreads();  // vmcnt drained by compiler before barrier
    bf16x8 af[4], bfr[4];
    #pragma unroll
    for (int i = 0; i < 4; ++i)
      af[i] = *(const bf16x8*)&At[(wm * 64 + i * 16 + ln) * 32 + quad * 8];
    #pragma unroll
    for (int j = 0; j < 4; ++j)
      bfr[j] = *(const bf16x8*)&Bt[(wn * 64 + j * 16 + ln) * 32 + quad * 8];
    #pragma unroll
    for (int i = 0; i < 4; ++i)
      #pragma unroll
      for (int j = 0; j < 4; ++j)
        acc[i][j] = __builtin_amdgcn_mfma_f32_16x16x32_bf16(af[i], bfr[j], acc[i][j], 0, 0, 0);
  }

  // epilogue: C/D layout col=lane&15, row=quad*4+reg
  #pragma unroll
  for (int i = 0; i < 4; ++i) {
    #pragma unroll
    for (int j = 0; j < 4; ++j) {
      #pragma unroll
      for (int r = 0; r < 4; ++r) {
        int gm = m0 + wm * 64 + i * 16 + quad * 4 + r;
        int gn = n0 + wn * 64 + j * 16 + ln;
        float v = acc[i][j][r] + bias[gn];
        if (MODE == 2) {
          outf[(uint64_t)gm * 1024 + gn] = v;
        } else if (MODE == 0) {
          int b = gm >> 10, a = gm & 1023;
          int which = gn >> 10, h = (gn >> 6) & 15, d = gn & 63;
          ushort_t val = f2bf(v);
          if (which == 0)
            Qb[((uint64_t)(b * H_ + h) * S_ + a) * HD_ + d] = val;
          else if (which == 1)
            Kb[((uint64_t)(b * H_ + h) * A_ + a) * HD_ + d] = val;
          else  // V stored transposed: (b,h,hd,A) for contiguous PV B-fragments
            Vb[((uint64_t)(b * H_ + h) * HD_ + d) * A_ + a] = val;
        } else {
          int b = (gm >= SQ_) ? 1 : 0; int sq = gm - b * SQ_;
          int h = gn >> 6, d = gn & 63;
          Qb[((uint64_t)(b * H_ + h) * S_ + (A_ + sq)) * HD_ + d] = f2bf(v);
        }
      }
    }
  }
}

// ---- MFMA flash attention: 128 Q-rows per block, 16 chunks of 64 keys ----
// S computed TRANSPOSED (S^T = K @ Q^T) so each lane's 4 acc regs are 4
// consecutive keys at fixed q -> P packs into ds_write_b64 into row-major
// Ps[q][key] (the layout PV's A-frags read vectorized). No max-subtraction
// (scores bounded); softmax denom via ones-row in Vt (PV n-tile j=4).
__global__ __launch_bounds__(256) void attn_mfma(const ushort_t* __restrict__ Qb,
                                                 const ushort_t* __restrict__ Kb,
                                                 const ushort_t* __restrict__ Vb,
                                                 ushort_t* __restrict__ Ob) {
  __shared__ __align__(16) ushort_t Ks[64 * 72];   // keys x hd, pad 8
  __shared__ __align__(16) ushort_t Vt[80 * 72];   // hd(+ones row 64) x keys, pad 8
  __shared__ __align__(16) ushort_t Ps[128 * 72];  // qrows x keys, pad 8
  const int t = threadIdx.x;
  const int lane = t & 63;
  const int quad = lane >> 4, ln = lane & 15;
  const int wave = t >> 6;
  const int wm = wave & 1, wn = wave >> 1;  // S^T: wm splits 64 keys, wn splits 128 q
  const int bh = blockIdx.y;
  const int b = bh >> 4, h = bh & 15;
  const int m0 = blockIdx.x * 128;

  // Q fragments (B-operand; B lane map == A lane map): q-rows wn*64+j*16+ln
  bf16x8 qf[4][2];
  {
    const ushort_t* qbase = Qb + ((uint64_t)bh * S_ + m0 + wn * 64 + ln) * HD_ + quad * 8;
    #pragma unroll
    for (int j = 0; j < 4; ++j)
      #pragma unroll
      for (int ks = 0; ks < 2; ++ks)
        qf[j][ks] = *(const bf16x8*)(qbase + (uint64_t)(j * 16) * HD_ + ks * 32);
  }
  // ones row (row 64 of Vt) -> PV n-tile j=4 col 64 accumulates the row sum
  if (t < 64) Vt[64 * 72 + t] = 0x3F80;  // bf16 1.0

  floatx4 oacc[2][5];
  #pragma unroll
  for (int i = 0; i < 2; ++i)
    #pragma unroll
    for (int j = 0; j < 5; ++j) oacc[i][j] = (floatx4)0.0f;

  const ushort_t* kcbase = Kb + (uint64_t)bh * A_ * HD_;
  const ushort_t* vcbase = Vb + (uint64_t)bh * HD_ * A_;
  const int srow = t >> 2, sseg = t & 3;  // staging: 4 threads/row, 16 elems each

  for (int kc = 0; kc < 16; ++kc) {
    const ushort_t* kg = kcbase + (uint64_t)(kc * 64 + srow) * 64 + sseg * 16;
    const ushort_t* vg = vcbase + (uint64_t)srow * A_ + kc * 64 + sseg * 16;
    ushort8 k0 = *(const ushort8*)kg;
    ushort8 k1 = *(const ushort8*)(kg + 8);
    ushort8 v0 = *(const ushort8*)vg;
    ushort8 v1 = *(const ushort8*)(vg + 8);
    __syncthreads();  // prev chunk's PV reads of Ks/Vt/Ps done
    *(ushort8*)&Ks[srow * 72 + sseg * 16] = k0;
    *(ushort8*)&Ks[srow * 72 + sseg * 16 + 8] = k1;
    *(ushort8*)&Vt[srow * 72 + sseg * 16] = v0;
    *(ushort8*)&Vt[srow * 72 + sseg * 16 + 8] = v1;
    __syncthreads();

    // S^T = K @ Q^T : wave computes keys [wm*32,+32) x q [wn*64,+64)
    floatx4 sacc[2][4];
    #pragma unroll
    for (int i = 0; i < 2; ++i)
      #pragma unroll
      for (int j = 0; j < 4; ++j) sacc[i][j] = (floatx4)0.0f;
    #pragma unroll
    for (int ks = 0; ks < 2; ++ks) {
      bf16x8 kf[2];
      #pragma unroll
      for (int i = 0; i < 2; ++i)
        kf[i] = *(const bf16x8*)&Ks[(wm * 32 + i * 16 + ln) * 72 + ks * 32 + quad * 8];
      #pragma unroll
      for (int i = 0; i < 2; ++i)
        #pragma unroll
        for (int j = 0; j < 4; ++j)
          sacc[i][j] = __builtin_amdgcn_mfma_f32_16x16x32_bf16(kf[i], qf[j][ks], sacc[i][j], 0, 0, 0);
    }
    // P = exp(S/8): lane holds keys (wm*32+i*16+quad*4+r), q = wn*64+j*16+ln
    // -> pack 4 consecutive keys into one b64 write at Ps[q][key0]
    #pragma unroll
    for (int i = 0; i < 2; ++i)
      #pragma unroll
      for (int j = 0; j < 4; ++j) {
        float p0 = __expf(sacc[i][j][0] * 0.125f);
        float p1 = __expf(sacc[i][j][1] * 0.125f);
        float p2 = __expf(sacc[i][j][2] * 0.125f);
        float p3 = __expf(sacc[i][j][3] * 0.125f);
        uint_t lo = (uint_t)f2bf(p0) | ((uint_t)f2bf(p1) << 16);
        uint_t hi = (uint_t)f2bf(p2) | ((uint_t)f2bf(p3) << 16);
        uint2v pk; pk[0] = lo; pk[1] = hi;
        int q = wn * 64 + j * 16 + ln;
        int key = wm * 32 + i * 16 + quad * 4;
        *(uint2v*)&Ps[q * 72 + key] = pk;
      }
    __syncthreads();

    // O += P @ V : wave owns 32 q-rows (wave*32), n-tiles j=0..4 (j=4 = row sum)
    #pragma unroll
    for (int ks = 0; ks < 2; ++ks) {
      bf16x8 af[2];
      #pragma unroll
      for (int i2 = 0; i2 < 2; ++i2)
        af[i2] = *(const bf16x8*)&Ps[(wave * 32 + i2 * 16 + ln) * 72 + ks * 32 + quad * 8];
      bf16x8 bv[5];
      #pragma unroll
      for (int j = 0; j < 5; ++j)
        bv[j] = *(const bf16x8*)&Vt[(j * 16 + ln) * 72 + ks * 32 + quad * 8];
      #pragma unroll
      for (int i2 = 0; i2 < 2; ++i2)
        #pragma unroll
        for (int j = 0; j < 5; ++j)
          oacc[i2][j] = __builtin_amdgcn_mfma_f32_16x16x32_bf16(af[i2], bv[j], oacc[i2][j], 0, 0, 0);
    }
  }

  // normalize + store: row sum lives in oacc[i2][4][r] on ln==0 lanes
  #pragma unroll
  for (int i2 = 0; i2 < 2; ++i2) {
    #pragma unroll
    for (int r = 0; r < 4; ++r) {
      float lsum = __shfl(oacc[i2][4][r], lane & 48);  // bcast from ln==0 of this quad
      float inv = 1.0f / lsum;
      int qrow = m0 + wave * 32 + i2 * 16 + quad * 4 + r;
      ushort_t* op = Ob + ((uint64_t)b * S_ + qrow) * D_ + h * HD_;
      #pragma unroll
      for (int j = 0; j < 4; ++j)
        op[j * 16 + ln] = f2bf(oacc[i2][j][r] * inv);
    }
  }
}

extern "C" void kernel_launch(void* const* d_in, const int* in_sizes, int n_in,
                              void* d_out, int out_size, void* d_ws, size_t ws_size,
                              hipStream_t stream) {
  (void)in_sizes; (void)n_in; (void)out_size; (void)ws_size;
  const float* x     = (const float*)d_in[0];
  const float* Wqkv  = (const float*)d_in[1];
  const float* bqkv  = (const float*)d_in[2];
  const float* Wq    = (const float*)d_in[3];
  const float* bq    = (const float*)d_in[4];
  const float* Wproj = (const float*)d_in[5];
  const float* bproj = (const float*)d_in[6];
  float* out = (float*)d_out;

  char* ws = (char*)d_ws;
  ushort_t* xb     = (ushort_t*)ws; ws += (size_t)B_ * S_ * D_ * 2;       // 32 MB
  ushort_t* wqkvT  = (ushort_t*)ws; ws += (size_t)3 * D_ * D_ * 2;        // 6 MB (3072x1024)
  ushort_t* wqT    = (ushort_t*)ws; ws += (size_t)D_ * D_ * 2;            // 2 MB
  ushort_t* wprojT = (ushort_t*)ws; ws += (size_t)D_ * D_ * 2;            // 2 MB
  ushort_t* Qb     = (ushort_t*)ws; ws += (size_t)B_ * H_ * S_ * HD_ * 2; // 32 MB (B,H,S,hd)
  ushort_t* Kb     = (ushort_t*)ws; ws += (size_t)B_ * H_ * A_ * HD_ * 2; // 4 MB (B,H,A,hd)
  ushort_t* Vb     = (ushort_t*)ws; ws += (size_t)B_ * H_ * A_ * HD_ * 2; // 4 MB (B,H,hd,A)
  ushort_t* Ob     = (ushort_t*)ws;                                       // 32 MB (B,S,D)

  cvt_x<<<dim3((B_ * S_ * D_) / (256 * 8)), dim3(256), 0, stream>>>(x, xb);
  cvt_wT<<<dim3(3072 / 32, 32), dim3(32, 8), 0, stream>>>(Wqkv, wqkvT, 3072);
  cvt_wT<<<dim3(1024 / 32, 32), dim3(32, 8), 0, stream>>>(Wq, wqT, 1024);
  cvt_wT<<<dim3(1024 / 32, 32), dim3(32, 8), 0, stream>>>(Wproj, wprojT, 1024);

  gemm_bt<0><<<dim3((B_ * A_) / 128, 3072 / 128), dim3(256), 0, stream>>>(
      xb, wqkvT, bqkv, Qb, Kb, Vb, nullptr);
  gemm_bt<1><<<dim3((B_ * SQ_) / 128, 1024 / 128), dim3(256), 0, stream>>>(
      xb, wqT, bq, Qb, nullptr, nullptr, nullptr);
  attn_mfma<<<dim3(S_ / 128, B_ * H_), dim3(256), 0, stream>>>(Qb, Kb, Vb, Ob);
  gemm_bt<2><<<dim3((B_ * S_) / 128, 1024 / 128), dim3(256), 0, stream>>>(
      Ob, wprojT, bproj, nullptr, nullptr, nullptr, out);
}